// Round 1
// baseline (491.586 us; speedup 1.0000x reference)
//
#include <hip/hip_runtime.h>
#include <hip/hip_bf16.h>

// Problem constants (from reference)
#define NUSERS   10000
#define NITEMS   100000
#define DIM      64
#define BATCH    4096

// GEMM tiling
#define KPAD     10016          // 313 * 32, zero-padded K
#define NSTEPS   313            // K-steps of 32
#define STEPS_PER_CHUNK 16
#define NCHUNK   20             // ceil(313/16)
#define MT       64             // batch rows per block
#define LSTR     40             // padded LDS row stride (bf16 elems), 32 + 8

typedef __bf16 bf16_t;
typedef __bf16 bf16x8 __attribute__((ext_vector_type(8)));
typedef float  f32x4  __attribute__((ext_vector_type(4)));

// ---------------------------------------------------------------------------
// Kernel 1: transpose + convert user_emb[k][d] (f32) -> ueT[d][k] (bf16),
// k zero-padded to KPAD so the GEMM K-loop needs no bounds checks on B.
// ---------------------------------------------------------------------------
__global__ void prep_ueT_kernel(const float* __restrict__ user_emb,
                                bf16_t* __restrict__ ueT) {
    int d = blockIdx.y;
    int k = blockIdx.x * 256 + threadIdx.x;
    if (k >= KPAD) return;
    float v = (k < NUSERS) ? user_emb[(size_t)k * DIM + d] : 0.0f;
    ueT[(size_t)d * KPAD + k] = (bf16_t)v;
}

// ---------------------------------------------------------------------------
// Kernel 2: out[b] = dot(user_emb[users[b]], item_emb[items[b]])
// Plain store — initializes d_out (poisoned by harness) before atomics.
// One wave per batch element.
// ---------------------------------------------------------------------------
__global__ void pos_kernel(const float* __restrict__ user_emb,
                           const float* __restrict__ item_emb,
                           const int* __restrict__ users,
                           const int* __restrict__ items,
                           float* __restrict__ out) {
    int w    = threadIdx.x >> 6;
    int lane = threadIdx.x & 63;
    int b    = blockIdx.x * 4 + w;
    if (b >= BATCH) return;
    int uid = users[b];
    int iid = items[b];
    float v = user_emb[(size_t)uid * DIM + lane] * item_emb[(size_t)iid * DIM + lane];
    v += __shfl_xor(v, 32, 64);
    v += __shfl_xor(v, 16, 64);
    v += __shfl_xor(v, 8, 64);
    v += __shfl_xor(v, 4, 64);
    v += __shfl_xor(v, 2, 64);
    v += __shfl_xor(v, 1, 64);
    if (lane == 0) out[b] = v;
}

// ---------------------------------------------------------------------------
// Kernel 3: social term.
//   V[m, d] = sum_k sw[users[m], k] * user_emb[k, d]   (bf16 MFMA GEMM)
//   out[m] += sum_d V[m, d] * item_emb[items[m], d]    (epilogue, atomicAdd)
// Grid: x = K-chunk (20), y = M-tile (64). Block 256 = 4 waves; each wave
// owns 16 rows x 64 cols via four 16x16x32 MFMA accumulators.
// ---------------------------------------------------------------------------
__global__ __launch_bounds__(256) void social_kernel(
        const float* __restrict__ sw,
        const bf16_t* __restrict__ ueT,
        const float* __restrict__ item_emb,
        const int* __restrict__ users,
        const int* __restrict__ items,
        float* __restrict__ out) {
    __shared__ bf16_t Atile[MT * LSTR];   // [row][k] sw tile, bf16
    __shared__ bf16_t Btile[DIM * LSTR];  // [n][k]  ueT tile, bf16
    __shared__ int uid_s[MT];

    const int tid = threadIdx.x;
    const int m0  = blockIdx.y * MT;
    const int s0  = blockIdx.x * STEPS_PER_CHUNK;
    const int s1  = (s0 + STEPS_PER_CHUNK < NSTEPS) ? s0 + STEPS_PER_CHUNK : NSTEPS;

    if (tid < MT) uid_s[tid] = users[m0 + tid];
    __syncthreads();

    // Staging mapping: thread -> (row 0..63, seg 0..3 -> k-offset 8*seg)
    const int srow = tid >> 2;
    const int sseg = tid & 3;
    const size_t a_row_base = (size_t)uid_s[srow] * NUSERS;

    // Compute mapping
    const int lane = tid & 63;
    const int w    = tid >> 6;       // wave id: rows [16w, 16w+16)
    const int q    = lane >> 4;      // quad group 0..3
    const int c    = lane & 15;

    f32x4 acc0 = {0.f, 0.f, 0.f, 0.f};
    f32x4 acc1 = {0.f, 0.f, 0.f, 0.f};
    f32x4 acc2 = {0.f, 0.f, 0.f, 0.f};
    f32x4 acc3 = {0.f, 0.f, 0.f, 0.f};

    for (int s = s0; s < s1; ++s) {
        const int k0 = s * 32;
        const int ka = k0 + 8 * sseg;

        // Issue global loads before the barrier (latency overlap).
        float4 a0 = {0.f, 0.f, 0.f, 0.f};
        float4 a1 = {0.f, 0.f, 0.f, 0.f};
        if (ka < NUSERS) {  // NUSERS % 8 == 0 -> whole 8-group in or out
            const float4* p = (const float4*)(sw + a_row_base + ka);
            a0 = p[0];
            a1 = p[1];
        }
        const bf16x8 bvec = *(const bf16x8*)(ueT + (size_t)srow * KPAD + ka);

        __syncthreads();  // all waves done reading LDS from previous step

        bf16x8 av;
        av[0] = (bf16_t)a0.x; av[1] = (bf16_t)a0.y;
        av[2] = (bf16_t)a0.z; av[3] = (bf16_t)a0.w;
        av[4] = (bf16_t)a1.x; av[5] = (bf16_t)a1.y;
        av[6] = (bf16_t)a1.z; av[7] = (bf16_t)a1.w;
        *(bf16x8*)(Atile + srow * LSTR + 8 * sseg) = av;
        *(bf16x8*)(Btile + srow * LSTR + 8 * sseg) = bvec;

        __syncthreads();  // tiles visible

        // Fragment reads: A[m=c][k=8q+j], B[k=8q+j][n] via k-contiguous LDS.
        const bf16x8 afrag = *(const bf16x8*)(Atile + (16 * w + c) * LSTR + 8 * q);
        const bf16x8 b0 = *(const bf16x8*)(Btile + (c     ) * LSTR + 8 * q);
        const bf16x8 b1 = *(const bf16x8*)(Btile + (c + 16) * LSTR + 8 * q);
        const bf16x8 b2 = *(const bf16x8*)(Btile + (c + 32) * LSTR + 8 * q);
        const bf16x8 b3 = *(const bf16x8*)(Btile + (c + 48) * LSTR + 8 * q);

        acc0 = __builtin_amdgcn_mfma_f32_16x16x32_bf16(afrag, b0, acc0, 0, 0, 0);
        acc1 = __builtin_amdgcn_mfma_f32_16x16x32_bf16(afrag, b1, acc1, 0, 0, 0);
        acc2 = __builtin_amdgcn_mfma_f32_16x16x32_bf16(afrag, b2, acc2, 0, 0, 0);
        acc3 = __builtin_amdgcn_mfma_f32_16x16x32_bf16(afrag, b3, acc3, 0, 0, 0);
    }

    // Epilogue: C/D layout (verified m89): col = lane&15, row = (lane>>4)*4 + r.
    // Row (local) = 16w + 4q + r; col of acc_t element = 16t + c.
    // out_partial[row] = sum_d C[row][d] * item_emb[items[row]][d]
    for (int r = 0; r < 4; ++r) {
        const int grow = m0 + 16 * w + 4 * q + r;
        const int iid  = items[grow];          // uniform across the 16-lane group
        const float* ie = item_emb + (size_t)iid * DIM;
        float v = acc0[r] * ie[c]
                + acc1[r] * ie[c + 16]
                + acc2[r] * ie[c + 32]
                + acc3[r] * ie[c + 48];
        // reduce across the 16 lanes (c = 0..15) holding this row
        v += __shfl_xor(v, 1, 64);
        v += __shfl_xor(v, 2, 64);
        v += __shfl_xor(v, 4, 64);
        v += __shfl_xor(v, 8, 64);
        if (c == 0) atomicAdd(out + grow, v);
    }
}

// ---------------------------------------------------------------------------
extern "C" void kernel_launch(void* const* d_in, const int* in_sizes, int n_in,
                              void* d_out, int out_size, void* d_ws, size_t ws_size,
                              hipStream_t stream) {
    const float* user_emb = (const float*)d_in[0];
    const float* item_emb = (const float*)d_in[1];
    const float* sw       = (const float*)d_in[2];
    const int*   users    = (const int*)d_in[3];
    const int*   items    = (const int*)d_in[4];
    float* out = (float*)d_out;

    bf16_t* ueT = (bf16_t*)d_ws;   // DIM * KPAD bf16 = 1.28 MB

    // 1) transpose+convert user_emb (runs every call; ws is re-poisoned)
    prep_ueT_kernel<<<dim3((KPAD + 255) / 256, DIM), 256, 0, stream>>>(user_emb, ueT);

    // 2) positive dot, initializes out
    pos_kernel<<<BATCH / 4, 256, 0, stream>>>(user_emb, item_emb, users, items, out);

    // 3) social GEMM + fused epilogue dot, atomic accumulate into out
    social_kernel<<<dim3(NCHUNK, BATCH / MT), 256, 0, stream>>>(
        sw, ueT, item_emb, users, items, out);
}